// Round 1
// baseline (948.367 us; speedup 1.0000x reference)
//
#include <hip/hip_runtime.h>
#include <hip/hip_bf16.h>
#include <stdint.h>

typedef unsigned short u16;
typedef __attribute__((ext_vector_type(8))) short bf16x8;   // 8 bf16 in 4 VGPRs
typedef __attribute__((ext_vector_type(4))) float f32x4;

#define NHEAD 16
#define NKVH  4
#define HDIM  128
#define TSEQ  2048
#define CEMB  2048
#define NB    4

__device__ __forceinline__ u16 f2bf(float f) {
  uint32_t u = __builtin_bit_cast(uint32_t, f);
  u += 0x7FFFu + ((u >> 16) & 1u);          // round to nearest even
  return (u16)(u >> 16);
}
__device__ __forceinline__ float bf2f(u16 h) {
  uint32_t u = ((uint32_t)h) << 16;
  return __builtin_bit_cast(float, u);
}

#define MFMA(a, b, c) __builtin_amdgcn_mfma_f32_16x16x32_bf16((a), (b), (c), 0, 0, 0)

__device__ __forceinline__ void gload_lds16(const u16* g, u16* l) {
  __builtin_amdgcn_global_load_lds((__attribute__((address_space(1))) void*)(g),
                                   (__attribute__((address_space(3))) void*)(l),
                                   16, 0, 0);
}

// ---------------- f32 -> bf16 convert ----------------
__global__ void cvt_kernel(const float* __restrict__ in, u16* __restrict__ out, int n4) {
  int stride = gridDim.x * blockDim.x;
  for (int i = blockIdx.x * blockDim.x + threadIdx.x; i < n4; i += stride) {
    float4 v = ((const float4*)in)[i];
    ushort4 o;
    o.x = f2bf(v.x); o.y = f2bf(v.y); o.z = f2bf(v.z); o.w = f2bf(v.w);
    ((ushort4*)out)[i] = o;
  }
}

// ---------------- RoPE (in-place, bf16 pairs) ----------------
__global__ void rope_kernel(u16* __restrict__ qk, const float* __restrict__ cosT,
                            const float* __restrict__ sinT, int npairs, float scale) {
  int idx = blockIdx.x * blockDim.x + threadIdx.x;
  if (idx >= npairs) return;
  int i = idx & 63;                 // pair index within head dim
  int t = (idx >> 6) & (TSEQ - 1);  // sequence position
  uint32_t v = ((uint32_t*)qk)[idx];
  float e = bf2f((u16)(v & 0xFFFFu));
  float o = bf2f((u16)(v >> 16));
  float c = cosT[t * 64 + i], s = sinT[t * 64 + i];
  float e2 = (e * c - o * s) * scale;
  float o2 = (e * s + o * c) * scale;
  ((uint32_t*)qk)[idx] = (uint32_t)f2bf(e2) | ((uint32_t)f2bf(o2) << 16);
}

// ---------------- bf16 B^T GEMM, 128x128 tile, BK=32 ----------------
// C[m][n] = sum_k A[m][k] * Bt[n][k], K = 2048 fixed, M = 8192 fixed.
// MODE: 0 = write Q [B,H,T,D] bf16; 1 = K [B,KVH,T,D] bf16; 2 = V^T [B,KVH,D,T] bf16;
//       3 = final f32 out [M][2048]
template <int MODE>
__global__ __launch_bounds__(256, 3) void gemm_bt(const u16* __restrict__ A,
                                                  const u16* __restrict__ Bt,
                                                  void* __restrict__ outp) {
  constexpr int K = 2048;
  __shared__ u16 As[128 * 32];
  __shared__ u16 Bs[128 * 32];
  const int tid = threadIdx.x;
  const int lane = tid & 63;
  const int w = tid >> 6;
  const int l15 = lane & 15;
  const int hi = lane >> 4;
  const int m0 = blockIdx.x * 128;
  const int n0 = blockIdx.y * 128;
  const int wm = (w >> 1) * 64;
  const int wn = (w & 1) * 64;

  // staging slots: chunk-linear index ci in [0,512); LDS holds logical chunk (ci&3)^((ci>>3)&3)
  const int ci0 = w * 64 + lane;
  const int ci1 = 256 + w * 64 + lane;
  const int rA0 = ci0 >> 2, rA1 = ci1 >> 2;
  const int cA0 = (ci0 & 3) ^ ((ci0 >> 3) & 3);
  const int cA1 = (ci1 & 3) ^ ((ci1 >> 3) & 3);
  const u16* gA0 = A + (size_t)(m0 + rA0) * K + cA0 * 8;
  const u16* gA1 = A + (size_t)(m0 + rA1) * K + cA1 * 8;
  const u16* gB0 = Bt + (size_t)(n0 + rA0) * K + cA0 * 8;
  const u16* gB1 = Bt + (size_t)(n0 + rA1) * K + cA1 * 8;
  u16* dA0 = As + (w * 64) * 8;
  u16* dA1 = As + (256 + w * 64) * 8;
  u16* dB0 = Bs + (w * 64) * 8;
  u16* dB1 = Bs + (256 + w * 64) * 8;

  f32x4 acc[4][4] = {};

  for (int kt = 0; kt < K; kt += 32) {
    gload_lds16(gA0 + kt, dA0);
    gload_lds16(gA1 + kt, dA1);
    gload_lds16(gB0 + kt, dB0);
    gload_lds16(gB1 + kt, dB1);
    __syncthreads();
    bf16x8 af[4], bfr[4];
#pragma unroll
    for (int i = 0; i < 4; i++) {
      int row = wm + i * 16 + l15;
      af[i] = *(const bf16x8*)&As[row * 32 + (hi ^ ((row >> 1) & 3)) * 8];
    }
#pragma unroll
    for (int j = 0; j < 4; j++) {
      int row = wn + j * 16 + l15;
      bfr[j] = *(const bf16x8*)&Bs[row * 32 + (hi ^ ((row >> 1) & 3)) * 8];
    }
#pragma unroll
    for (int i = 0; i < 4; i++)
#pragma unroll
      for (int j = 0; j < 4; j++) acc[i][j] = MFMA(af[i], bfr[j], acc[i][j]);
    __syncthreads();
  }

  // epilogue
#pragma unroll
  for (int i = 0; i < 4; i++)
#pragma unroll
    for (int j = 0; j < 4; j++)
#pragma unroll
      for (int r = 0; r < 4; r++) {
        int m = m0 + wm + i * 16 + hi * 4 + r;
        int n = n0 + wn + j * 16 + l15;
        float v = acc[i][j][r];
        if (MODE == 3) {
          ((float*)outp)[(size_t)m * CEMB + n] = v;
        } else {
          int b = m >> 11, t = m & (TSEQ - 1);
          u16 bv = f2bf(v);
          if (MODE == 0) {
            int h = n >> 7, d = n & 127;
            ((u16*)outp)[(((size_t)(b * NHEAD + h) * TSEQ + t) << 7) + d] = bv;
          } else if (MODE == 1) {
            int kh = n >> 7, d = n & 127;
            ((u16*)outp)[(((size_t)(b * NKVH + kh) * TSEQ + t) << 7) + d] = bv;
          } else {
            int kh = n >> 7, d = n & 127;
            ((u16*)outp)[((size_t)(b * NKVH + kh) * HDIM + d) * TSEQ + t] = bv;
          }
        }
      }
}

// ---------------- causal GQA flash attention ----------------
// grid: (16 qtiles, 64 bh). 4 waves, each owns 32 q rows. KV tile = 64.
__global__ __launch_bounds__(256, 2) void attn_kernel(const u16* __restrict__ q,
                                                      const u16* __restrict__ k,
                                                      const u16* __restrict__ vT,
                                                      u16* __restrict__ ao) {
  __shared__ u16 Ps[4][32][72];  // per-wave private P staging, padded stride 72
  const int tid = threadIdx.x;
  const int lane = tid & 63;
  const int w = tid >> 6;
  const int l15 = lane & 15;
  const int hi = lane >> 4;
  const int qt = 15 - (int)blockIdx.x;  // heavy tiles dispatched first
  const int bh = blockIdx.y;
  const int b = bh >> 4, h = bh & 15;
  const int kvh = h >> 2;  // n_rep = 4

  const u16* qbase = q + (size_t)(b * NHEAD + h) * TSEQ * HDIM;
  const u16* kbase = k + (size_t)(b * NKVH + kvh) * TSEQ * HDIM;
  const u16* vbase = vT + (size_t)(b * NKVH + kvh) * HDIM * TSEQ;

  // Q fragments in registers: 2 m-frags x 4 k-steps
  bf16x8 qf[2][4];
#pragma unroll
  for (int mf = 0; mf < 2; mf++)
#pragma unroll
    for (int ks = 0; ks < 4; ks++)
      qf[mf][ks] = *(const bf16x8*)(qbase + (size_t)(qt * 128 + w * 32 + mf * 16 + l15) * HDIM +
                                    ks * 32 + hi * 8);

  f32x4 o[2][8] = {};
  float mrow[2][4], lrow[2][4];
#pragma unroll
  for (int mf = 0; mf < 2; mf++)
#pragma unroll
    for (int r = 0; r < 4; r++) { mrow[mf][r] = -1e30f; lrow[mf][r] = 0.0f; }

  const int jmax = 2 * qt + 1;
  for (int j = 0; j <= jmax; j++) {
    // ---- S = Q K^T (scale folded into q by rope kernel) ----
    f32x4 s[2][4] = {};
#pragma unroll
    for (int nf = 0; nf < 4; nf++) {
      const u16* kr = kbase + (size_t)(j * 64 + nf * 16 + l15) * HDIM + hi * 8;
#pragma unroll
      for (int ks = 0; ks < 4; ks++) {
        bf16x8 kf = *(const bf16x8*)(kr + ks * 32);
        s[0][nf] = MFMA(qf[0][ks], kf, s[0][nf]);
        s[1][nf] = MFMA(qf[1][ks], kf, s[1][nf]);
      }
    }
    // ---- causal mask (only last two kv tiles) ----
    if (j >= (qt << 1)) {
#pragma unroll
      for (int mf = 0; mf < 2; mf++)
#pragma unroll
        for (int nf = 0; nf < 4; nf++)
#pragma unroll
          for (int r = 0; r < 4; r++) {
            int kj = j * 64 + nf * 16 + l15;
            int qi = (qt << 7) + w * 32 + mf * 16 + (hi << 2) + r;
            if (kj > qi) s[mf][nf][r] = -1e30f;
          }
    }
    // ---- online softmax (rows live in (hi,r); reduce across lane&15 and nf) ----
#pragma unroll
    for (int mf = 0; mf < 2; mf++) {
#pragma unroll
      for (int r = 0; r < 4; r++) {
        float rm = fmaxf(fmaxf(s[mf][0][r], s[mf][1][r]), fmaxf(s[mf][2][r], s[mf][3][r]));
        rm = fmaxf(rm, __shfl_xor(rm, 1));
        rm = fmaxf(rm, __shfl_xor(rm, 2));
        rm = fmaxf(rm, __shfl_xor(rm, 4));
        rm = fmaxf(rm, __shfl_xor(rm, 8));
        float mn = fmaxf(mrow[mf][r], rm);
        float alpha = __expf(mrow[mf][r] - mn);
        mrow[mf][r] = mn;
        float rs = 0.0f;
#pragma unroll
        for (int nf = 0; nf < 4; nf++) {
          float pv = __expf(s[mf][nf][r] - mn);
          s[mf][nf][r] = pv;
          rs += pv;
        }
        rs += __shfl_xor(rs, 1);
        rs += __shfl_xor(rs, 2);
        rs += __shfl_xor(rs, 4);
        rs += __shfl_xor(rs, 8);
        lrow[mf][r] = lrow[mf][r] * alpha + rs;
#pragma unroll
        for (int nb = 0; nb < 8; nb++) o[mf][nb][r] *= alpha;
      }
      // write P tile rows for this mf (per-wave private LDS; same-wave RAW handled by compiler)
#pragma unroll
      for (int nf = 0; nf < 4; nf++)
#pragma unroll
        for (int r = 0; r < 4; r++)
          Ps[w][mf * 16 + hi * 4 + r][nf * 16 + l15] = f2bf(s[mf][nf][r]);
    }
    // ---- O += P V  (V^T rows are contiguous in t) ----
#pragma unroll
    for (int ks2 = 0; ks2 < 2; ks2++) {
      bf16x8 pa0 = *(const bf16x8*)&Ps[w][l15][ks2 * 32 + hi * 8];
      bf16x8 pa1 = *(const bf16x8*)&Ps[w][16 + l15][ks2 * 32 + hi * 8];
      const u16* vr = vbase + (size_t)l15 * TSEQ + j * 64 + ks2 * 32 + hi * 8;
#pragma unroll
      for (int nb = 0; nb < 8; nb++) {
        bf16x8 vf = *(const bf16x8*)(vr + (size_t)nb * 16 * TSEQ);
        o[0][nb] = MFMA(pa0, vf, o[0][nb]);
        o[1][nb] = MFMA(pa1, vf, o[1][nb]);
      }
    }
  }

  // ---- epilogue: normalize and scatter to [B*T][C] bf16 ----
#pragma unroll
  for (int mf = 0; mf < 2; mf++)
#pragma unroll
    for (int r = 0; r < 4; r++) {
      float inv = 1.0f / lrow[mf][r];
      int t = qt * 128 + w * 32 + mf * 16 + hi * 4 + r;
      u16* orow = ao + (size_t)(b * TSEQ + t) * CEMB + h * HDIM;
#pragma unroll
      for (int nb = 0; nb < 8; nb++) orow[nb * 16 + l15] = f2bf(o[mf][nb][r] * inv);
    }
}

// ---------------- launcher ----------------
extern "C" void kernel_launch(void* const* d_in, const int* in_sizes, int n_in,
                              void* d_out, int out_size, void* d_ws, size_t ws_size,
                              hipStream_t stream) {
  const float* x  = (const float*)d_in[0];
  const float* wq = (const float*)d_in[1];
  const float* wk = (const float*)d_in[2];
  const float* wv = (const float*)d_in[3];
  const float* wo = (const float*)d_in[4];
  const float* rc = (const float*)d_in[5];
  const float* rs = (const float*)d_in[6];

  char* ws = (char*)d_ws;
  u16* xb  = (u16*)(ws);                 // 32 MiB  x bf16 [8192][2048]
  u16* qb  = (u16*)(ws + 33554432);      // 32 MiB  q [B][H][T][D]
  u16* kb  = (u16*)(ws + 67108864);      // 8 MiB   k [B][KVH][T][D]
  u16* vTb = (u16*)(ws + 75497472);      // 8 MiB   v^T [B][KVH][D][T]
  u16* aob = (u16*)(ws + 83886080);      // 32 MiB  attn out [8192][2048]
  u16* wqb = (u16*)(ws + 117440512);     // 8 MiB
  u16* wkb = (u16*)(ws + 125829120);     // 2 MiB
  u16* wvb = (u16*)(ws + 127926272);     // 2 MiB
  u16* wob = (u16*)(ws + 130023424);     // 8 MiB

  cvt_kernel<<<2048, 256, 0, stream>>>(x, xb, 16777216 / 4);
  cvt_kernel<<<1024, 256, 0, stream>>>(wq, wqb, 4194304 / 4);
  cvt_kernel<<<512, 256, 0, stream>>>(wk, wkb, 1048576 / 4);
  cvt_kernel<<<512, 256, 0, stream>>>(wv, wvb, 1048576 / 4);
  cvt_kernel<<<1024, 256, 0, stream>>>(wo, wob, 4194304 / 4);

  gemm_bt<0><<<dim3(64, 16), 256, 0, stream>>>(xb, wqb, qb);
  gemm_bt<1><<<dim3(64, 4), 256, 0, stream>>>(xb, wkb, kb);
  gemm_bt<2><<<dim3(64, 4), 256, 0, stream>>>(xb, wvb, vTb);

  // rope: q gets 1/sqrt(128) folded in; k unscaled
  rope_kernel<<<32768, 256, 0, stream>>>(qb, rc, rs, NB * NHEAD * TSEQ * 64,
                                         0.08838834764831845f);
  rope_kernel<<<8192, 256, 0, stream>>>(kb, rc, rs, NB * NKVH * TSEQ * 64, 1.0f);

  attn_kernel<<<dim3(16, 64), 256, 0, stream>>>(qb, kb, vTb, aob);

  gemm_bt<3><<<dim3(64, 16), 256, 0, stream>>>(aob, wob, d_out);
}

// Round 3
// 670.568 us; speedup vs baseline: 1.4143x; 1.4143x over previous
//
#include <hip/hip_runtime.h>
#include <hip/hip_bf16.h>
#include <stdint.h>

typedef unsigned short u16;
typedef __attribute__((ext_vector_type(8))) short bf16x8;   // 8 bf16 in 4 VGPRs
typedef __attribute__((ext_vector_type(4))) float f32x4;

#define NHEAD 16
#define NKVH  4
#define HDIM  128
#define TSEQ  2048
#define CEMB  2048
#define NB    4

__device__ __forceinline__ u16 f2bf(float f) {
  uint32_t u = __builtin_bit_cast(uint32_t, f);
  u += 0x7FFFu + ((u >> 16) & 1u);          // round to nearest even
  return (u16)(u >> 16);
}
__device__ __forceinline__ float bf2f(u16 h) {
  uint32_t u = ((uint32_t)h) << 16;
  return __builtin_bit_cast(float, u);
}

#define MFMA(a, b, c) __builtin_amdgcn_mfma_f32_16x16x32_bf16((a), (b), (c), 0, 0, 0)

__device__ __forceinline__ void gload_lds16(const u16* g, u16* l) {
  __builtin_amdgcn_global_load_lds((__attribute__((address_space(1))) void*)(g),
                                   (__attribute__((address_space(3))) void*)(l),
                                   16, 0, 0);
}

// ---------------- f32 -> bf16 convert ----------------
__global__ void cvt_kernel(const float* __restrict__ in, u16* __restrict__ out, int n4) {
  int stride = gridDim.x * blockDim.x;
  for (int i = blockIdx.x * blockDim.x + threadIdx.x; i < n4; i += stride) {
    float4 v = ((const float4*)in)[i];
    ushort4 o;
    o.x = f2bf(v.x); o.y = f2bf(v.y); o.z = f2bf(v.z); o.w = f2bf(v.w);
    ((ushort4*)out)[i] = o;
  }
}

// ---------------- RoPE (in-place, bf16 pairs) ----------------
__global__ void rope_kernel(u16* __restrict__ qk, const float* __restrict__ cosT,
                            const float* __restrict__ sinT, int npairs, float scale) {
  int idx = blockIdx.x * blockDim.x + threadIdx.x;
  if (idx >= npairs) return;
  int i = idx & 63;                 // pair index within head dim
  int t = (idx >> 6) & (TSEQ - 1);  // sequence position
  uint32_t v = ((uint32_t*)qk)[idx];
  float e = bf2f((u16)(v & 0xFFFFu));
  float o = bf2f((u16)(v >> 16));
  float c = cosT[t * 64 + i], s = sinT[t * 64 + i];
  float e2 = (e * c - o * s) * scale;
  float o2 = (e * s + o * c) * scale;
  ((uint32_t*)qk)[idx] = (uint32_t)f2bf(e2) | ((uint32_t)f2bf(o2) << 16);
}

// ---------------- bf16 B^T GEMM, 128x128 tile, BK=32 ----------------
// C[m][n] = sum_k A[m][k] * Bt[n][k], K = 2048 fixed, M = 8192 fixed.
// MODE: 0 = write Q [B,H,T,D] bf16; 1 = K [B,KVH,T,D] bf16; 2 = V^T [B,KVH,D,T] bf16;
//       3 = final f32 out [M][2048]
template <int MODE>
__global__ __launch_bounds__(256, 3) void gemm_bt(const u16* __restrict__ A,
                                                  const u16* __restrict__ Bt,
                                                  void* __restrict__ outp) {
  constexpr int K = 2048;
  __shared__ u16 As[128 * 32];
  __shared__ u16 Bs[128 * 32];
  const int tid = threadIdx.x;
  const int lane = tid & 63;
  const int w = tid >> 6;
  const int l15 = lane & 15;
  const int hi = lane >> 4;
  const int m0 = blockIdx.x * 128;
  const int n0 = blockIdx.y * 128;
  const int wm = (w >> 1) * 64;
  const int wn = (w & 1) * 64;

  // staging slots: chunk-linear index ci in [0,512); LDS holds logical chunk (ci&3)^((ci>>3)&3)
  const int ci0 = w * 64 + lane;
  const int ci1 = 256 + w * 64 + lane;
  const int rA0 = ci0 >> 2, rA1 = ci1 >> 2;
  const int cA0 = (ci0 & 3) ^ ((ci0 >> 3) & 3);
  const int cA1 = (ci1 & 3) ^ ((ci1 >> 3) & 3);
  const u16* gA0 = A + (size_t)(m0 + rA0) * K + cA0 * 8;
  const u16* gA1 = A + (size_t)(m0 + rA1) * K + cA1 * 8;
  const u16* gB0 = Bt + (size_t)(n0 + rA0) * K + cA0 * 8;
  const u16* gB1 = Bt + (size_t)(n0 + rA1) * K + cA1 * 8;
  u16* dA0 = As + (w * 64) * 8;
  u16* dA1 = As + (256 + w * 64) * 8;
  u16* dB0 = Bs + (w * 64) * 8;
  u16* dB1 = Bs + (256 + w * 64) * 8;

  f32x4 acc[4][4] = {};

  for (int kt = 0; kt < K; kt += 32) {
    gload_lds16(gA0 + kt, dA0);
    gload_lds16(gA1 + kt, dA1);
    gload_lds16(gB0 + kt, dB0);
    gload_lds16(gB1 + kt, dB1);
    __syncthreads();
    bf16x8 af[4], bfr[4];
#pragma unroll
    for (int i = 0; i < 4; i++) {
      int row = wm + i * 16 + l15;
      af[i] = *(const bf16x8*)&As[row * 32 + (hi ^ ((row >> 1) & 3)) * 8];
    }
#pragma unroll
    for (int j = 0; j < 4; j++) {
      int row = wn + j * 16 + l15;
      bfr[j] = *(const bf16x8*)&Bs[row * 32 + (hi ^ ((row >> 1) & 3)) * 8];
    }
#pragma unroll
    for (int i = 0; i < 4; i++)
#pragma unroll
      for (int j = 0; j < 4; j++) acc[i][j] = MFMA(af[i], bfr[j], acc[i][j]);
    __syncthreads();
  }

  // epilogue
#pragma unroll
  for (int i = 0; i < 4; i++)
#pragma unroll
    for (int j = 0; j < 4; j++)
#pragma unroll
      for (int r = 0; r < 4; r++) {
        int m = m0 + wm + i * 16 + hi * 4 + r;
        int n = n0 + wn + j * 16 + l15;
        float v = acc[i][j][r];
        if (MODE == 3) {
          ((float*)outp)[(size_t)m * CEMB + n] = v;
        } else {
          int b = m >> 11, t = m & (TSEQ - 1);
          u16 bv = f2bf(v);
          if (MODE == 0) {
            int h = n >> 7, d = n & 127;
            ((u16*)outp)[(((size_t)(b * NHEAD + h) * TSEQ + t) << 7) + d] = bv;
          } else if (MODE == 1) {
            int kh = n >> 7, d = n & 127;
            ((u16*)outp)[(((size_t)(b * NKVH + kh) * TSEQ + t) << 7) + d] = bv;
          } else {
            int kh = n >> 7, d = n & 127;
            ((u16*)outp)[((size_t)(b * NKVH + kh) * HDIM + d) * TSEQ + t] = bv;
          }
        }
      }
}

// ---------------- causal GQA flash attention, v2 ----------------
// grid: (8 qtile-pairs, 64 bh). Each block processes q-tiles (15-bx) then (bx):
// every block does exactly 34 KV-iterations (perfect balance). 4 waves, each
// owns 32 q rows. KV tile = 64. K/V fragment loads are batched into register
// arrays so their L1/L2 latency is amortized (one exposure per batch) and V's
// latency hides under softmax + P staging.
__global__ __launch_bounds__(256, 2) void attn_kernel(const u16* __restrict__ q,
                                                      const u16* __restrict__ k,
                                                      const u16* __restrict__ vT,
                                                      u16* __restrict__ ao) {
  __shared__ u16 Ps[4][32][72];  // per-wave private P staging, padded stride 72
  const int tid = threadIdx.x;
  const int lane = tid & 63;
  const int w = tid >> 6;
  const int l15 = lane & 15;
  const int hi = lane >> 4;
  const int bh = blockIdx.y;
  const int b = bh >> 4, h = bh & 15;
  const int kvh = h >> 2;  // n_rep = 4

  const u16* qbase = q + (size_t)(b * NHEAD + h) * TSEQ * HDIM;
  const u16* kbase = k + (size_t)(b * NKVH + kvh) * TSEQ * HDIM;
  const u16* vbase = vT + (size_t)(b * NKVH + kvh) * HDIM * TSEQ;

#pragma unroll 1
  for (int pass = 0; pass < 2; ++pass) {
    const int qt = pass == 0 ? 15 - (int)blockIdx.x : (int)blockIdx.x;

    // Q fragments in registers: 2 m-frags x 4 k-steps
    bf16x8 qf[2][4];
#pragma unroll
    for (int mf = 0; mf < 2; mf++)
#pragma unroll
      for (int ks = 0; ks < 4; ks++)
        qf[mf][ks] = *(const bf16x8*)(qbase +
                                      (size_t)(qt * 128 + w * 32 + mf * 16 + l15) * HDIM +
                                      ks * 32 + hi * 8);

    f32x4 o[2][8] = {};
    float mrow[2][4], lrow[2][4];
#pragma unroll
    for (int mf = 0; mf < 2; mf++)
#pragma unroll
      for (int r = 0; r < 4; r++) { mrow[mf][r] = -1e30f; lrow[mf][r] = 0.0f; }

    const int jmax = 2 * qt + 1;
#pragma unroll 1
    for (int j = 0; j <= jmax; j++) {
      // ---- batched K fragment load (one latency exposure, 16 loads in flight)
      bf16x8 kf[4][4];
      const u16* kr = kbase + (size_t)(j * 64) * HDIM;
#pragma unroll
      for (int nf = 0; nf < 4; nf++)
#pragma unroll
        for (int ks = 0; ks < 4; ks++)
          kf[nf][ks] = *(const bf16x8*)(kr + (size_t)(nf * 16 + l15) * HDIM + ks * 32 + hi * 8);

      // ---- S = Q K^T (scale folded into q by rope kernel) ----
      f32x4 s[2][4] = {};
#pragma unroll
      for (int nf = 0; nf < 4; nf++)
#pragma unroll
        for (int ks = 0; ks < 4; ks++) {
          s[0][nf] = MFMA(qf[0][ks], kf[nf][ks], s[0][nf]);
          s[1][nf] = MFMA(qf[1][ks], kf[nf][ks], s[1][nf]);
        }

      // ---- batched V fragment load; latency hides under softmax + P staging
      bf16x8 vf[2][8];
#pragma unroll
      for (int ks2 = 0; ks2 < 2; ks2++) {
        const u16* vr = vbase + (size_t)l15 * TSEQ + j * 64 + ks2 * 32 + hi * 8;
#pragma unroll
        for (int nb = 0; nb < 8; nb++)
          vf[ks2][nb] = *(const bf16x8*)(vr + (size_t)nb * 16 * TSEQ);
      }

      // ---- causal mask (only last two kv tiles) ----
      if (j >= (qt << 1)) {
#pragma unroll
        for (int mf = 0; mf < 2; mf++)
#pragma unroll
          for (int nf = 0; nf < 4; nf++)
#pragma unroll
            for (int r = 0; r < 4; r++) {
              int kj = j * 64 + nf * 16 + l15;
              int qi = (qt << 7) + w * 32 + mf * 16 + (hi << 2) + r;
              if (kj > qi) s[mf][nf][r] = -1e30f;
            }
      }

      // ---- online softmax (rows live in (hi,r); reduce across lane&15) ----
#pragma unroll
      for (int mf = 0; mf < 2; mf++) {
#pragma unroll
        for (int r = 0; r < 4; r++) {
          float rm = fmaxf(fmaxf(s[mf][0][r], s[mf][1][r]), fmaxf(s[mf][2][r], s[mf][3][r]));
          rm = fmaxf(rm, __shfl_xor(rm, 1));
          rm = fmaxf(rm, __shfl_xor(rm, 2));
          rm = fmaxf(rm, __shfl_xor(rm, 4));
          rm = fmaxf(rm, __shfl_xor(rm, 8));
          float mn = fmaxf(mrow[mf][r], rm);
          float alpha = __expf(mrow[mf][r] - mn);
          mrow[mf][r] = mn;
          float rs = 0.0f;
#pragma unroll
          for (int nf = 0; nf < 4; nf++) {
            float pv = __expf(s[mf][nf][r] - mn);
            s[mf][nf][r] = pv;
            rs += pv;
          }
          rs += __shfl_xor(rs, 1);
          rs += __shfl_xor(rs, 2);
          rs += __shfl_xor(rs, 4);
          rs += __shfl_xor(rs, 8);
          lrow[mf][r] = lrow[mf][r] * alpha + rs;
#pragma unroll
          for (int nb = 0; nb < 8; nb++) o[mf][nb][r] *= alpha;
        }
        // write P tile rows for this mf (per-wave private LDS)
#pragma unroll
        for (int nf = 0; nf < 4; nf++)
#pragma unroll
          for (int r = 0; r < 4; r++)
            Ps[w][mf * 16 + hi * 4 + r][nf * 16 + l15] = f2bf(s[mf][nf][r]);
      }

      // ---- O += P V  (V fragments already in registers) ----
#pragma unroll
      for (int ks2 = 0; ks2 < 2; ks2++) {
        bf16x8 pa0 = *(const bf16x8*)&Ps[w][l15][ks2 * 32 + hi * 8];
        bf16x8 pa1 = *(const bf16x8*)&Ps[w][16 + l15][ks2 * 32 + hi * 8];
#pragma unroll
        for (int nb = 0; nb < 8; nb++) {
          o[0][nb] = MFMA(pa0, vf[ks2][nb], o[0][nb]);
          o[1][nb] = MFMA(pa1, vf[ks2][nb], o[1][nb]);
        }
      }
    }

    // ---- epilogue: normalize and scatter to [B*T][C] bf16 ----
#pragma unroll
    for (int mf = 0; mf < 2; mf++)
#pragma unroll
      for (int r = 0; r < 4; r++) {
        float inv = 1.0f / lrow[mf][r];
        int t = qt * 128 + w * 32 + mf * 16 + hi * 4 + r;
        u16* orow = ao + (size_t)(b * TSEQ + t) * CEMB + h * HDIM;
#pragma unroll
        for (int nb = 0; nb < 8; nb++) orow[nb * 16 + l15] = f2bf(o[mf][nb][r] * inv);
      }
  }
}

// ---------------- launcher ----------------
extern "C" void kernel_launch(void* const* d_in, const int* in_sizes, int n_in,
                              void* d_out, int out_size, void* d_ws, size_t ws_size,
                              hipStream_t stream) {
  const float* x  = (const float*)d_in[0];
  const float* wq = (const float*)d_in[1];
  const float* wk = (const float*)d_in[2];
  const float* wv = (const float*)d_in[3];
  const float* wo = (const float*)d_in[4];
  const float* rc = (const float*)d_in[5];
  const float* rs = (const float*)d_in[6];

  char* ws = (char*)d_ws;
  u16* xb  = (u16*)(ws);                 // 32 MiB  x bf16 [8192][2048]
  u16* qb  = (u16*)(ws + 33554432);      // 32 MiB  q [B][H][T][D]
  u16* kb  = (u16*)(ws + 67108864);      // 8 MiB   k [B][KVH][T][D]
  u16* vTb = (u16*)(ws + 75497472);      // 8 MiB   v^T [B][KVH][D][T]
  u16* aob = (u16*)(ws + 83886080);      // 32 MiB  attn out [8192][2048]
  u16* wqb = (u16*)(ws + 117440512);     // 8 MiB
  u16* wkb = (u16*)(ws + 125829120);     // 2 MiB
  u16* wvb = (u16*)(ws + 127926272);     // 2 MiB
  u16* wob = (u16*)(ws + 130023424);     // 8 MiB

  cvt_kernel<<<2048, 256, 0, stream>>>(x, xb, 16777216 / 4);
  cvt_kernel<<<1024, 256, 0, stream>>>(wq, wqb, 4194304 / 4);
  cvt_kernel<<<512, 256, 0, stream>>>(wk, wkb, 1048576 / 4);
  cvt_kernel<<<512, 256, 0, stream>>>(wv, wvb, 1048576 / 4);
  cvt_kernel<<<1024, 256, 0, stream>>>(wo, wob, 4194304 / 4);

  gemm_bt<0><<<dim3(64, 16), 256, 0, stream>>>(xb, wqb, qb);
  gemm_bt<1><<<dim3(64, 4), 256, 0, stream>>>(xb, wkb, kb);
  gemm_bt<2><<<dim3(64, 4), 256, 0, stream>>>(xb, wvb, vTb);

  // rope: q gets 1/sqrt(128) folded in; k unscaled
  rope_kernel<<<32768, 256, 0, stream>>>(qb, rc, rs, NB * NHEAD * TSEQ * 64,
                                         0.08838834764831845f);
  rope_kernel<<<8192, 256, 0, stream>>>(kb, rc, rs, NB * NKVH * TSEQ * 64, 1.0f);

  attn_kernel<<<dim3(8, 64), 256, 0, stream>>>(qb, kb, vTb, aob);

  gemm_bt<3><<<dim3(64, 16), 256, 0, stream>>>(aob, wob, d_out);
}

// Round 4
// 607.976 us; speedup vs baseline: 1.5599x; 1.1030x over previous
//
#include <hip/hip_runtime.h>
#include <hip/hip_bf16.h>
#include <stdint.h>

typedef unsigned short u16;
typedef __attribute__((ext_vector_type(8))) short bf16x8;   // 8 bf16 in 4 VGPRs
typedef __attribute__((ext_vector_type(4))) float f32x4;

#define NHEAD 16
#define NKVH  4
#define HDIM  128
#define TSEQ  2048
#define CEMB  2048
#define NB    4

__device__ __forceinline__ u16 f2bf(float f) {
  uint32_t u = __builtin_bit_cast(uint32_t, f);
  u += 0x7FFFu + ((u >> 16) & 1u);          // round to nearest even
  return (u16)(u >> 16);
}
__device__ __forceinline__ float bf2f(u16 h) {
  uint32_t u = ((uint32_t)h) << 16;
  return __builtin_bit_cast(float, u);
}

#define MFMA(a, b, c) __builtin_amdgcn_mfma_f32_16x16x32_bf16((a), (b), (c), 0, 0, 0)

__device__ __forceinline__ void gload_lds16(const u16* g, u16* l) {
  __builtin_amdgcn_global_load_lds((__attribute__((address_space(1))) void*)(g),
                                   (__attribute__((address_space(3))) void*)(l),
                                   16, 0, 0);
}

// ---------------- f32 -> bf16 convert ----------------
__global__ void cvt_kernel(const float* __restrict__ in, u16* __restrict__ out, int n4) {
  int stride = gridDim.x * blockDim.x;
  for (int i = blockIdx.x * blockDim.x + threadIdx.x; i < n4; i += stride) {
    float4 v = ((const float4*)in)[i];
    ushort4 o;
    o.x = f2bf(v.x); o.y = f2bf(v.y); o.z = f2bf(v.z); o.w = f2bf(v.w);
    ((ushort4*)out)[i] = o;
  }
}

// ---------------- RoPE (in-place, bf16 pairs) ----------------
__global__ void rope_kernel(u16* __restrict__ qk, const float* __restrict__ cosT,
                            const float* __restrict__ sinT, int npairs, float scale) {
  int idx = blockIdx.x * blockDim.x + threadIdx.x;
  if (idx >= npairs) return;
  int i = idx & 63;                 // pair index within head dim
  int t = (idx >> 6) & (TSEQ - 1);  // sequence position
  uint32_t v = ((uint32_t*)qk)[idx];
  float e = bf2f((u16)(v & 0xFFFFu));
  float o = bf2f((u16)(v >> 16));
  float c = cosT[t * 64 + i], s = sinT[t * 64 + i];
  float e2 = (e * c - o * s) * scale;
  float o2 = (e * s + o * c) * scale;
  ((uint32_t*)qk)[idx] = (uint32_t)f2bf(e2) | ((uint32_t)f2bf(o2) << 16);
}

// ---------------- bf16 B^T GEMM, 128x128 tile, BK=32 ----------------
// C[m][n] = sum_k A[m][k] * Bt[n][k], K = 2048 fixed, M = 8192 fixed.
// MODE: 0 = write Q [B,H,T,D] bf16; 1 = K [B,KVH,T,D] bf16; 2 = V^T [B,KVH,D,T] bf16;
//       3 = final f32 out [M][2048]
template <int MODE>
__global__ __launch_bounds__(256, 3) void gemm_bt(const u16* __restrict__ A,
                                                  const u16* __restrict__ Bt,
                                                  void* __restrict__ outp) {
  constexpr int K = 2048;
  __shared__ u16 As[128 * 32];
  __shared__ u16 Bs[128 * 32];
  const int tid = threadIdx.x;
  const int lane = tid & 63;
  const int w = tid >> 6;
  const int l15 = lane & 15;
  const int hi = lane >> 4;
  const int m0 = blockIdx.x * 128;
  const int n0 = blockIdx.y * 128;
  const int wm = (w >> 1) * 64;
  const int wn = (w & 1) * 64;

  // staging slots: chunk-linear index ci in [0,512); LDS holds logical chunk (ci&3)^((ci>>3)&3)
  const int ci0 = w * 64 + lane;
  const int ci1 = 256 + w * 64 + lane;
  const int rA0 = ci0 >> 2, rA1 = ci1 >> 2;
  const int cA0 = (ci0 & 3) ^ ((ci0 >> 3) & 3);
  const int cA1 = (ci1 & 3) ^ ((ci1 >> 3) & 3);
  const u16* gA0 = A + (size_t)(m0 + rA0) * K + cA0 * 8;
  const u16* gA1 = A + (size_t)(m0 + rA1) * K + cA1 * 8;
  const u16* gB0 = Bt + (size_t)(n0 + rA0) * K + cA0 * 8;
  const u16* gB1 = Bt + (size_t)(n0 + rA1) * K + cA1 * 8;
  u16* dA0 = As + (w * 64) * 8;
  u16* dA1 = As + (256 + w * 64) * 8;
  u16* dB0 = Bs + (w * 64) * 8;
  u16* dB1 = Bs + (256 + w * 64) * 8;

  f32x4 acc[4][4] = {};

  for (int kt = 0; kt < K; kt += 32) {
    gload_lds16(gA0 + kt, dA0);
    gload_lds16(gA1 + kt, dA1);
    gload_lds16(gB0 + kt, dB0);
    gload_lds16(gB1 + kt, dB1);
    __syncthreads();
    bf16x8 af[4], bfr[4];
#pragma unroll
    for (int i = 0; i < 4; i++) {
      int row = wm + i * 16 + l15;
      af[i] = *(const bf16x8*)&As[row * 32 + (hi ^ ((row >> 1) & 3)) * 8];
    }
#pragma unroll
    for (int j = 0; j < 4; j++) {
      int row = wn + j * 16 + l15;
      bfr[j] = *(const bf16x8*)&Bs[row * 32 + (hi ^ ((row >> 1) & 3)) * 8];
    }
#pragma unroll
    for (int i = 0; i < 4; i++)
#pragma unroll
      for (int j = 0; j < 4; j++) acc[i][j] = MFMA(af[i], bfr[j], acc[i][j]);
    __syncthreads();
  }

  // epilogue
#pragma unroll
  for (int i = 0; i < 4; i++)
#pragma unroll
    for (int j = 0; j < 4; j++)
#pragma unroll
      for (int r = 0; r < 4; r++) {
        int m = m0 + wm + i * 16 + hi * 4 + r;
        int n = n0 + wn + j * 16 + l15;
        float v = acc[i][j][r];
        if (MODE == 3) {
          ((float*)outp)[(size_t)m * CEMB + n] = v;
        } else {
          int b = m >> 11, t = m & (TSEQ - 1);
          u16 bv = f2bf(v);
          if (MODE == 0) {
            int h = n >> 7, d = n & 127;
            ((u16*)outp)[(((size_t)(b * NHEAD + h) * TSEQ + t) << 7) + d] = bv;
          } else if (MODE == 1) {
            int kh = n >> 7, d = n & 127;
            ((u16*)outp)[(((size_t)(b * NKVH + kh) * TSEQ + t) << 7) + d] = bv;
          } else {
            int kh = n >> 7, d = n & 127;
            ((u16*)outp)[((size_t)(b * NKVH + kh) * HDIM + d) * TSEQ + t] = bv;
          }
        }
      }
}

// ---------------- causal GQA flash attention, v3 (LDS-staged K/V) ----------------
// grid: (16 qtile-pairs, 64 bh). Each block: q-tiles (31-bx) then (bx) = 34 iters.
// 4 waves x 16 q-rows = QBLK 64. KV tile 64, K/V DMA'd to LDS via global_load_lds
// (single-buffered, m97 pattern: sync / compute / sync / stage-next). Both tiles
// XOR-swizzled via pre-swizzled global source so ds_read_b128 is conflict-free.
// LDS = 16K(K)+16K(V)+8K(P) = 40960B exactly -> 4 blocks/CU; VGPR<=128 -> 16 waves/CU.
// Softmax in base-2 (log2e folded into q scale) with defer-max rescale skip.
__global__ __launch_bounds__(256, 4) void attn_kernel(const u16* __restrict__ q,
                                                      const u16* __restrict__ k,
                                                      const u16* __restrict__ vT,
                                                      u16* __restrict__ ao) {
  __shared__ u16 Ks[64 * 128];   // [kv row][d], rows 256B, 16B-slot ^= (row&15)
  __shared__ u16 Vs[128 * 64];   // [d row][t], rows 128B, 16B-slot ^= (row&7)
  __shared__ u16 Ps[4 * 16 * 64];// per-wave [q row][kv], rows 128B, slot ^= (row&7)
  const int tid = threadIdx.x;
  const int lane = tid & 63;
  const int w = tid >> 6;
  const int l15 = lane & 15;
  const int hi = lane >> 4;
  const int bh = blockIdx.y;
  const int b = bh >> 4, h = bh & 15;
  const int kvh = h >> 2;  // n_rep = 4

  const u16* qbase = q + (size_t)(b * NHEAD + h) * TSEQ * HDIM;
  const u16* kbase = k + (size_t)(b * NKVH + kvh) * TSEQ * HDIM;
  const u16* vbase = vT + (size_t)(b * NKVH + kvh) * HDIM * TSEQ;

  // stage KV tile j into LDS: 4+4 global_load_lds_dwordx4 per wave.
  // Global source is pre-swizzled so LDS (linear dest) holds the swizzled layout.
  auto stage = [&](int j) {
    const u16* kt = kbase + (size_t)(j * 64) * HDIM;
#pragma unroll
    for (int c = 0; c < 4; c++) {
      int ci = w * 256 + c * 64 + lane;
      int row = ci >> 4;
      int sl = (ci & 15) ^ (row & 15);
      gload_lds16(kt + row * 128 + sl * 8, Ks + (w * 256 + c * 64) * 8);
    }
#pragma unroll
    for (int c = 0; c < 4; c++) {
      int ci = w * 256 + c * 64 + lane;
      int row = ci >> 3;
      int sl = (ci & 7) ^ (row & 7);
      gload_lds16(vbase + (size_t)row * TSEQ + j * 64 + sl * 8,
                  Vs + (w * 256 + c * 64) * 8);
    }
  };

#pragma unroll 1
  for (int pass = 0; pass < 2; ++pass) {
    const int qt = pass == 0 ? 31 - (int)blockIdx.x : (int)blockIdx.x;
    const int qrow0 = qt * 64 + w * 16;

    // Q fragments in registers (4 k-steps x 16 rows per wave)
    bf16x8 qf[4];
#pragma unroll
    for (int ks = 0; ks < 4; ks++)
      qf[ks] = *(const bf16x8*)(qbase + (size_t)(qrow0 + l15) * HDIM + ks * 32 + hi * 8);

    f32x4 o[8] = {};
    float mrow[4], lrow[4];
#pragma unroll
    for (int r = 0; r < 4; r++) { mrow[r] = -1e30f; lrow[r] = 0.0f; }

    stage(0);

#pragma unroll 1
    for (int j = 0; j <= qt; j++) {
      __syncthreads();  // DMA for tile j complete (vmcnt drained at barrier)

      // ---- S = Q K^T from LDS (swizzled reads, conflict-free) ----
      f32x4 s[4] = {};
#pragma unroll
      for (int nf = 0; nf < 4; nf++) {
        const u16* krow = Ks + (nf * 16 + l15) * 128;
#pragma unroll
        for (int ks = 0; ks < 4; ks++) {
          bf16x8 kf = *(const bf16x8*)(krow + (((ks * 4 + hi) ^ l15)) * 8);
          s[nf] = MFMA(qf[ks], kf, s[nf]);
        }
      }

      // ---- causal mask (only diagonal tile) ----
      if (j == qt) {
#pragma unroll
        for (int nf = 0; nf < 4; nf++)
#pragma unroll
          for (int r = 0; r < 4; r++) {
            int kj = j * 64 + nf * 16 + l15;
            int qi = qrow0 + hi * 4 + r;
            if (kj > qi) s[nf][r] = -1e30f;
          }
      }

      // ---- online softmax, base-2, defer-max ----
      float pm[4];
#pragma unroll
      for (int r = 0; r < 4; r++) {
        float rm = fmaxf(fmaxf(s[0][r], s[1][r]), fmaxf(s[2][r], s[3][r]));
        rm = fmaxf(rm, __shfl_xor(rm, 1));
        rm = fmaxf(rm, __shfl_xor(rm, 2));
        rm = fmaxf(rm, __shfl_xor(rm, 4));
        rm = fmaxf(rm, __shfl_xor(rm, 8));
        pm[r] = rm;
      }
      bool need = (pm[0] > mrow[0] + 11.f) || (pm[1] > mrow[1] + 11.f) ||
                  (pm[2] > mrow[2] + 11.f) || (pm[3] > mrow[3] + 11.f);
      if (__any(need)) {
#pragma unroll
        for (int r = 0; r < 4; r++) {
          float mn = fmaxf(mrow[r], pm[r]);
          float al = exp2f(mrow[r] - mn);
          mrow[r] = mn;
          lrow[r] *= al;
#pragma unroll
          for (int nb = 0; nb < 8; nb++) o[nb][r] *= al;
        }
      }
#pragma unroll
      for (int r = 0; r < 4; r++) {
        float rs = 0.0f;
#pragma unroll
        for (int nf = 0; nf < 4; nf++) {
          float pv = exp2f(s[nf][r] - mrow[r]);
          s[nf][r] = pv;
          rs += pv;
        }
        rs += __shfl_xor(rs, 1);
        rs += __shfl_xor(rs, 2);
        rs += __shfl_xor(rs, 4);
        rs += __shfl_xor(rs, 8);
        lrow[r] += rs;
        int row = hi * 4 + r;
#pragma unroll
        for (int nf = 0; nf < 4; nf++)
          Ps[w * 1024 + row * 64 + ((nf * 16 + l15) ^ ((row & 7) << 3))] = f2bf(s[nf][r]);
      }

      // ---- O += P V from LDS ----
#pragma unroll
      for (int ks2 = 0; ks2 < 2; ks2++) {
        int sl = ((ks2 * 4 + hi) ^ (l15 & 7)) * 8;
        bf16x8 pa = *(const bf16x8*)(Ps + w * 1024 + l15 * 64 + sl);
#pragma unroll
        for (int nb = 0; nb < 8; nb++) {
          bf16x8 vf = *(const bf16x8*)(Vs + (nb * 16 + l15) * 64 + sl);
          o[nb] = MFMA(pa, vf, o[nb]);
        }
      }

      __syncthreads();  // all waves done reading Ks/Vs before overwrite
      if (j < qt) stage(j + 1);
    }

    // ---- epilogue: normalize and scatter to [B*T][C] bf16 ----
#pragma unroll
    for (int r = 0; r < 4; r++) {
      float inv = 1.0f / lrow[r];
      int t = qrow0 + hi * 4 + r;
      u16* orow = ao + (size_t)(b * TSEQ + t) * CEMB + h * HDIM;
#pragma unroll
      for (int nb = 0; nb < 8; nb++) orow[nb * 16 + l15] = f2bf(o[nb][r] * inv);
    }
  }
}

// ---------------- launcher ----------------
extern "C" void kernel_launch(void* const* d_in, const int* in_sizes, int n_in,
                              void* d_out, int out_size, void* d_ws, size_t ws_size,
                              hipStream_t stream) {
  const float* x  = (const float*)d_in[0];
  const float* wq = (const float*)d_in[1];
  const float* wk = (const float*)d_in[2];
  const float* wv = (const float*)d_in[3];
  const float* wo = (const float*)d_in[4];
  const float* rc = (const float*)d_in[5];
  const float* rs = (const float*)d_in[6];

  char* ws = (char*)d_ws;
  u16* xb  = (u16*)(ws);                 // 32 MiB  x bf16 [8192][2048]
  u16* qb  = (u16*)(ws + 33554432);      // 32 MiB  q [B][H][T][D]
  u16* kb  = (u16*)(ws + 67108864);      // 8 MiB   k [B][KVH][T][D]
  u16* vTb = (u16*)(ws + 75497472);      // 8 MiB   v^T [B][KVH][D][T]
  u16* aob = (u16*)(ws + 83886080);      // 32 MiB  attn out [8192][2048]
  u16* wqb = (u16*)(ws + 117440512);     // 8 MiB
  u16* wkb = (u16*)(ws + 125829120);     // 2 MiB
  u16* wvb = (u16*)(ws + 127926272);     // 2 MiB
  u16* wob = (u16*)(ws + 130023424);     // 8 MiB

  cvt_kernel<<<2048, 256, 0, stream>>>(x, xb, 16777216 / 4);
  cvt_kernel<<<1024, 256, 0, stream>>>(wq, wqb, 4194304 / 4);
  cvt_kernel<<<512, 256, 0, stream>>>(wk, wkb, 1048576 / 4);
  cvt_kernel<<<512, 256, 0, stream>>>(wv, wvb, 1048576 / 4);
  cvt_kernel<<<1024, 256, 0, stream>>>(wo, wob, 4194304 / 4);

  gemm_bt<0><<<dim3(64, 16), 256, 0, stream>>>(xb, wqb, qb);
  gemm_bt<1><<<dim3(64, 4), 256, 0, stream>>>(xb, wkb, kb);
  gemm_bt<2><<<dim3(64, 4), 256, 0, stream>>>(xb, wvb, vTb);

  // rope: q gets (1/sqrt(128))*log2(e) folded in (softmax runs in base 2); k unscaled
  rope_kernel<<<32768, 256, 0, stream>>>(qb, rc, rs, NB * NHEAD * TSEQ * 64,
                                         0.12751744646620015f);
  rope_kernel<<<8192, 256, 0, stream>>>(kb, rc, rs, NB * NKVH * TSEQ * 64, 1.0f);

  attn_kernel<<<dim3(16, 64), 256, 0, stream>>>(qb, kb, vTb, aob);

  gemm_bt<3><<<dim3(64, 16), 256, 0, stream>>>(aob, wob, d_out);
}